// Round 1
// baseline (916.152 us; speedup 1.0000x reference)
//
#include <hip/hip_runtime.h>
#include <hip/hip_bf16.h>

// ---------------- problem constants ----------------
#define T_TOK   4096          // B*S
#define DIM     1024
#define NEXP    8
#define HID     4096
#define CAPPAD  9216          // max padded routed rows: 2*T + 8*127 -> round to 128-mult
#define MTOT    (CAPPAD + T_TOK)   // 13312 = routed(+pad) rows + shared rows
// MTOT must be a multiple of 128 for the tail-free GEMM grid
static_assert(MTOT % 128 == 0, "MTOT must be multiple of 128");

typedef __attribute__((ext_vector_type(8))) short bf16x8;
typedef __attribute__((ext_vector_type(4))) float f32x4;

typedef const __attribute__((address_space(1))) unsigned int* gas1_u32;
typedef __attribute__((address_space(3))) unsigned int* las3_u32;

__device__ __forceinline__ void async_ld16(const void* g, void* l) {
    // global -> LDS direct DMA, 16B per lane. LDS dest must be wave-uniform base + lane*16.
    __builtin_amdgcn_global_load_lds((gas1_u32)g, (las3_u32)l, 16, 0, 0);
}

__device__ __forceinline__ unsigned short f2bf(float f) {
    union { float f; unsigned u; } v; v.f = f;
    unsigned r = v.u + 0x7fffu + ((v.u >> 16) & 1u);   // RNE
    return (unsigned short)(r >> 16);
}

// ---------------- router: fp32 logits, softmax, top-2 ----------------
__global__ __launch_bounds__(256)
void router_kernel(const float* __restrict__ x, const float* __restrict__ rw,
                   const float* __restrict__ rb, int* __restrict__ cnt,
                   int* __restrict__ top_e, float* __restrict__ top_w) {
    const int tid  = threadIdx.x;
    const int lane = tid & 63;
    const int t    = blockIdx.x * 4 + (tid >> 6);       // one token per wave
    const float* xr = x + (size_t)t * DIM;
    float acc[NEXP];
#pragma unroll
    for (int e = 0; e < NEXP; ++e) acc[e] = 0.f;
    for (int d = lane; d < DIM; d += 64) {
        float xv = xr[d];
        const float* r = rw + (size_t)d * NEXP;         // coalesced: lane l reads row d=l..., 32B each
#pragma unroll
        for (int e = 0; e < NEXP; ++e) acc[e] += xv * r[e];
    }
#pragma unroll
    for (int off = 32; off > 0; off >>= 1) {
#pragma unroll
        for (int e = 0; e < NEXP; ++e) acc[e] += __shfl_down(acc[e], off);
    }
    if (lane == 0) {
        float lg[NEXP], p[NEXP];
        float mx = -1e30f;
#pragma unroll
        for (int e = 0; e < NEXP; ++e) { lg[e] = acc[e] + rb[e]; mx = fmaxf(mx, lg[e]); }
        float s = 0.f;
#pragma unroll
        for (int e = 0; e < NEXP; ++e) { p[e] = expf(lg[e] - mx); s += p[e]; }
        float inv = 1.f / s;
#pragma unroll
        for (int e = 0; e < NEXP; ++e) p[e] *= inv;
        int i1 = 0;
#pragma unroll
        for (int e = 1; e < NEXP; ++e) if (p[e] > p[i1]) i1 = e;   // strict > == lowest-index tie rule
        int i2 = (i1 == 0) ? 1 : 0;
#pragma unroll
        for (int e = 0; e < NEXP; ++e) if (e != i1 && p[e] > p[i2]) i2 = e;
        top_e[2 * t]     = i1;  top_w[2 * t]     = p[i1];
        top_e[2 * t + 1] = i2;  top_w[2 * t + 1] = p[i2];
        atomicAdd(&cnt[i1], 1);
        atomicAdd(&cnt[i2], 1);
    }
}

// ---------------- per-expert 128-aligned segment offsets ----------------
__global__ void offsets_kernel(const int* __restrict__ cnt, int* __restrict__ poff) {
    if (threadIdx.x == 0) {
        int acc = 0;
#pragma unroll
        for (int e = 0; e < NEXP; ++e) { poff[e] = acc; acc += (cnt[e] + 127) & ~127; }
        poff[NEXP] = acc;   // padded total (<= CAPPAD)
    }
}

// ---------------- slot assignment ----------------
__global__ __launch_bounds__(256)
void assign_kernel(const int* __restrict__ top_e, const int* __restrict__ poff,
                   int* __restrict__ cursor, int* __restrict__ slot_of,
                   int* __restrict__ rowtok) {
    int t = blockIdx.x * 256 + threadIdx.x;
#pragma unroll
    for (int k = 0; k < 2; ++k) {
        int e = top_e[2 * t + k];
        int s = poff[e] + atomicAdd(&cursor[e], 1);
        slot_of[2 * t + k] = s;
        rowtok[s] = t;
    }
}

// ---------------- gather + fp32->bf16 convert (routed rows, zero pads, shared rows) ----------------
__global__ __launch_bounds__(256)
void gather_kernel(const float* __restrict__ x, const int* __restrict__ rowtok,
                   unsigned short* __restrict__ xg) {
    int row = blockIdx.x;
    int t = (row >= CAPPAD) ? (row - CAPPAD) : rowtok[row];
    ushort4* dst = (ushort4*)(xg + (size_t)row * DIM) + threadIdx.x;
    if (t < 0) { ushort4 z; z.x = z.y = z.z = z.w = 0; *dst = z; return; }
    float4 v = ((const float4*)(x + (size_t)t * DIM))[threadIdx.x];
    ushort4 o; o.x = f2bf(v.x); o.y = f2bf(v.y); o.z = f2bf(v.z); o.w = f2bf(v.w);
    *dst = o;
}

// ---------------- transpose + convert: fp32 [R][C] -> bf16 [C][R] (B^T for GEMM) ----------------
__global__ __launch_bounds__(256)
void transpose_convert(const float* __restrict__ in, unsigned short* __restrict__ out,
                       int R, int C) {
    __shared__ float tile[64][65];
    const size_t bofs = (size_t)blockIdx.z * R * C;
    in += bofs; out += bofs;
    const int r0 = blockIdx.y * 64, c0 = blockIdx.x * 64;
    const int tc = threadIdx.x & 63, tr = threadIdx.x >> 6;
#pragma unroll
    for (int j = 0; j < 16; ++j)
        tile[tr + j * 4][tc] = in[(size_t)(r0 + tr + j * 4) * C + c0 + tc];
    __syncthreads();
#pragma unroll
    for (int j = 0; j < 16; ++j)
        out[(size_t)(c0 + tr + j * 4) * R + r0 + tc] = f2bf(tile[tc][tr + j * 4]);
}

// ---------------- bf16 MFMA GEMM, m97 structure: 128x128 tile, BK=64, global_load_lds ----------------
// A: [MTOT][K] bf16 row-major. Weights: Wt [NEXP][N][K] bf16 (B^T), SWt [N][K] for shared rows.
// GELU=true: out = bf16 H[row][N] = gelu(acc + bias). GELU=false: out = f32 Y[row][N] = acc + bias.
template <int N, int K, bool GELU>
__global__ __launch_bounds__(256, 2)
void gemm_kernel(const unsigned short* __restrict__ A,
                 const unsigned short* __restrict__ Wt,
                 const unsigned short* __restrict__ SWt,
                 const float* __restrict__ Bias, const float* __restrict__ SBias,
                 const int* __restrict__ poff, void* __restrict__ Out) {
    __shared__ unsigned short As[128 * 64];
    __shared__ unsigned short Bs[128 * 64];
    const int tid = threadIdx.x, lane = tid & 63;
    const int wr = tid >> 7, wc = (tid >> 6) & 1;      // 2x2 waves, 64x64 per wave
    const int row0 = blockIdx.y * 128, col0 = blockIdx.x * 128;

    const unsigned short* Bt; const float* bias;
    if (row0 >= CAPPAD) { Bt = SWt; bias = SBias; }
    else {
        int e = 0;
#pragma unroll
        for (int i = 1; i < NEXP; ++i) e += (row0 >= poff[i]);
        Bt = Wt + (size_t)e * N * K; bias = Bias + (size_t)e * N;
    }

    f32x4 acc[4][4];
#pragma unroll
    for (int m = 0; m < 4; ++m)
#pragma unroll
        for (int n = 0; n < 4; ++n) acc[m][n] = (f32x4){0.f, 0.f, 0.f, 0.f};

    for (int kt = 0; kt < K / 64; ++kt) {
        const int kb = kt * 64;
#pragma unroll
        for (int j = 0; j < 4; ++j) {
            int c  = j * 256 + tid;        // 16B chunk id; per wave: uniform base + lane*16
            int r  = c >> 3, k8 = c & 7;
            async_ld16(A  + (size_t)(row0 + r) * K + kb + k8 * 8, As + c * 8);
            async_ld16(Bt + (size_t)(col0 + r) * K + kb + k8 * 8, Bs + c * 8);
        }
        __syncthreads();                   // compiler drains vmcnt before s_barrier
#pragma unroll
        for (int kk = 0; kk < 2; ++kk) {
            bf16x8 af[4], bfr[4];
#pragma unroll
            for (int m = 0; m < 4; ++m)
                af[m] = *(const bf16x8*)(As + (wr * 64 + m * 16 + (lane & 15)) * 64 + kk * 32 + (lane >> 4) * 8);
#pragma unroll
            for (int n = 0; n < 4; ++n)
                bfr[n] = *(const bf16x8*)(Bs + (wc * 64 + n * 16 + (lane & 15)) * 64 + kk * 32 + (lane >> 4) * 8);
#pragma unroll
            for (int m = 0; m < 4; ++m)
#pragma unroll
                for (int n = 0; n < 4; ++n)
                    acc[m][n] = __builtin_amdgcn_mfma_f32_16x16x32_bf16(af[m], bfr[n], acc[m][n], 0, 0, 0);
        }
        __syncthreads();
    }

    // epilogue: C/D layout col=lane&15, row=(lane>>4)*4+j
    const int rb_ = row0 + wr * 64 + ((lane >> 4) << 2);
#pragma unroll
    for (int n = 0; n < 4; ++n) {
        const int col = col0 + wc * 64 + n * 16 + (lane & 15);
        const float bv = bias[col];
#pragma unroll
        for (int m = 0; m < 4; ++m) {
#pragma unroll
            for (int j = 0; j < 4; ++j) {
                const int row = rb_ + m * 16 + j;
                float v = acc[m][n][j] + bv;
                if (GELU) {
                    v = 0.5f * v * (1.f + erff(v * 0.70710678118654752f));  // exact GELU
                    ((unsigned short*)Out)[(size_t)row * N + col] = f2bf(v);
                } else {
                    ((float*)Out)[(size_t)row * N + col] = v;
                }
            }
        }
    }
}

// ---------------- final combine: out = shared + w0*expert0 + w1*expert1 ----------------
__global__ __launch_bounds__(256)
void combine_kernel(const float* __restrict__ Y, const int* __restrict__ slot_of,
                    const float* __restrict__ top_w, float* __restrict__ out) {
    const int t = blockIdx.x, i = threadIdx.x;
    const int s0 = slot_of[2 * t], s1 = slot_of[2 * t + 1];
    const float w0 = top_w[2 * t], w1 = top_w[2 * t + 1];
    float4 ys = ((const float4*)(Y + (size_t)(CAPPAD + t) * DIM))[i];
    float4 y0 = ((const float4*)(Y + (size_t)s0 * DIM))[i];
    float4 y1 = ((const float4*)(Y + (size_t)s1 * DIM))[i];
    float4 r;
    r.x = ys.x + w0 * y0.x + w1 * y1.x;
    r.y = ys.y + w0 * y0.y + w1 * y1.y;
    r.z = ys.z + w0 * y0.z + w1 * y1.z;
    r.w = ys.w + w0 * y0.w + w1 * y1.w;
    ((float4*)(out + (size_t)t * DIM))[i] = r;
}

// ---------------- host launch ----------------
extern "C" void kernel_launch(void* const* d_in, const int* in_sizes, int n_in,
                              void* d_out, int out_size, void* d_ws, size_t ws_size,
                              hipStream_t stream) {
    const float* x   = (const float*)d_in[0];
    const float* rw  = (const float*)d_in[1];
    const float* rb  = (const float*)d_in[2];
    const float* w1  = (const float*)d_in[3];
    const float* b1  = (const float*)d_in[4];
    const float* w2  = (const float*)d_in[5];
    const float* b2  = (const float*)d_in[6];
    const float* sw1 = (const float*)d_in[7];
    const float* sb1 = (const float*)d_in[8];
    const float* sw2 = (const float*)d_in[9];
    const float* sb2 = (const float*)d_in[10];
    float* out = (float*)d_out;

    char* ws = (char*)d_ws;
    size_t off = 0;
    auto alloc = [&](size_t bytes) {
        off = (off + 255) & ~(size_t)255;
        size_t p = off; off += bytes; return p;
    };
    // meta: [0..7]=cnt, [8..15]=cursor, [16..24]=poff
    int*   meta    = (int*)(ws + alloc(32 * sizeof(int)));
    int*   cnt     = meta;
    int*   cursor  = meta + 8;
    int*   poff    = meta + 16;
    int*   top_e   = (int*)  (ws + alloc((size_t)2 * T_TOK * 4));
    float* top_w   = (float*)(ws + alloc((size_t)2 * T_TOK * 4));
    int*   slot_of = (int*)  (ws + alloc((size_t)2 * T_TOK * 4));
    int*   rowtok  = (int*)  (ws + alloc((size_t)CAPPAD * 4));
    unsigned short* xg   = (unsigned short*)(ws + alloc((size_t)MTOT * DIM * 2));
    unsigned short* w1t  = (unsigned short*)(ws + alloc((size_t)NEXP * HID * DIM * 2));
    unsigned short* w2t  = (unsigned short*)(ws + alloc((size_t)NEXP * DIM * HID * 2));
    unsigned short* sw1t = (unsigned short*)(ws + alloc((size_t)HID * DIM * 2));
    unsigned short* sw2t = (unsigned short*)(ws + alloc((size_t)DIM * HID * 2));
    unsigned short* H    = (unsigned short*)(ws + alloc((size_t)MTOT * HID * 2));
    float*          Y    = (float*)         (ws + alloc((size_t)MTOT * DIM * 4));
    // total ws use ~342 MB

    hipMemsetAsync(meta, 0, 16 * sizeof(int), stream);          // cnt + cursor = 0
    hipMemsetAsync(rowtok, 0xFF, (size_t)CAPPAD * 4, stream);   // rowtok = -1

    // weight transpose+convert: fp32 [R][C] -> bf16 [C][R]
    transpose_convert<<<dim3(HID / 64, DIM / 64, NEXP), 256, 0, stream>>>(w1,  w1t,  DIM, HID);
    transpose_convert<<<dim3(DIM / 64, HID / 64, NEXP), 256, 0, stream>>>(w2,  w2t,  HID, DIM);
    transpose_convert<<<dim3(HID / 64, DIM / 64, 1),    256, 0, stream>>>(sw1, sw1t, DIM, HID);
    transpose_convert<<<dim3(DIM / 64, HID / 64, 1),    256, 0, stream>>>(sw2, sw2t, HID, DIM);

    router_kernel<<<T_TOK / 4, 256, 0, stream>>>(x, rw, rb, cnt, top_e, top_w);
    offsets_kernel<<<1, 64, 0, stream>>>(cnt, poff);
    assign_kernel<<<T_TOK / 256, 256, 0, stream>>>(top_e, poff, cursor, slot_of, rowtok);
    gather_kernel<<<MTOT, 256, 0, stream>>>(x, rowtok, xg);

    gemm_kernel<HID, DIM, true ><<<dim3(HID / 128, MTOT / 128), 256, 0, stream>>>(
        xg, w1t, sw1t, b1, sb1, poff, (void*)H);
    gemm_kernel<DIM, HID, false><<<dim3(DIM / 128, MTOT / 128), 256, 0, stream>>>(
        H, w2t, sw2t, b2, sb2, poff, (void*)Y);

    combine_kernel<<<T_TOK, 256, 0, stream>>>(Y, slot_of, top_w, out);
}

// Round 4
// 880.504 us; speedup vs baseline: 1.0405x; 1.0405x over previous
//
#include <hip/hip_runtime.h>
#include <hip/hip_bf16.h>

// ---------------- problem constants ----------------
#define T_TOK   4096          // B*S
#define DIM     1024
#define NEXP    8
#define HID     4096
#define CAPPAD  10240         // max padded routed rows: 2*T + 8*255 -> round to 256-mult
#define MTOT    (CAPPAD + T_TOK)   // 14336 = routed(+pad) rows + shared rows
static_assert(MTOT % 256 == 0, "MTOT must be multiple of 256");
static_assert(CAPPAD % 256 == 0, "CAPPAD must be multiple of 256");

typedef __attribute__((ext_vector_type(8))) short bf16x8;
typedef __attribute__((ext_vector_type(4))) float f32x4;

typedef const __attribute__((address_space(1))) unsigned int* gas1_u32;
typedef __attribute__((address_space(3))) unsigned int* las3_u32;

__device__ __forceinline__ void async_ld16(const void* g, void* l) {
    // global -> LDS direct DMA, 16B per lane. LDS dest must be wave-uniform base + lane*16.
    __builtin_amdgcn_global_load_lds((gas1_u32)g, (las3_u32)l, 16, 0, 0);
}

__device__ __forceinline__ unsigned short f2bf(float f) {
    union { float f; unsigned u; } v; v.f = f;
    unsigned r = v.u + 0x7fffu + ((v.u >> 16) & 1u);   // RNE
    return (unsigned short)(r >> 16);
}

#define BAR() do { asm volatile("" ::: "memory"); __builtin_amdgcn_s_barrier(); asm volatile("" ::: "memory"); } while (0)
#define VMCNT4() asm volatile("s_waitcnt vmcnt(4)" ::: "memory")
#define VMCNT2() asm volatile("s_waitcnt vmcnt(2)" ::: "memory")
#define VMCNT0() asm volatile("s_waitcnt vmcnt(0)" ::: "memory")

__device__ __forceinline__ int xcd_swizzle(int wg, int nwg) {
    // m204 bijective XCD swizzle (8 XCDs)
    int q = nwg >> 3, r = nwg & 7;
    int x = wg & 7, i = wg >> 3;
    return (x < r ? x * (q + 1) : r * (q + 1) + (x - r) * q) + i;
}

// ---------------- router: fp32 logits, softmax, top-2 ----------------
__global__ __launch_bounds__(256)
void router_kernel(const float* __restrict__ x, const float* __restrict__ rw,
                   const float* __restrict__ rb, int* __restrict__ cnt,
                   int* __restrict__ top_e, float* __restrict__ top_w) {
    const int tid  = threadIdx.x;
    const int lane = tid & 63;
    const int t    = blockIdx.x * 4 + (tid >> 6);       // one token per wave
    const float* xr = x + (size_t)t * DIM;
    float acc[NEXP];
#pragma unroll
    for (int e = 0; e < NEXP; ++e) acc[e] = 0.f;
    for (int d = lane; d < DIM; d += 64) {
        float xv = xr[d];
        const float* r = rw + (size_t)d * NEXP;
#pragma unroll
        for (int e = 0; e < NEXP; ++e) acc[e] += xv * r[e];
    }
#pragma unroll
    for (int off = 32; off > 0; off >>= 1) {
#pragma unroll
        for (int e = 0; e < NEXP; ++e) acc[e] += __shfl_down(acc[e], off);
    }
    if (lane == 0) {
        float lg[NEXP], p[NEXP];
        float mx = -1e30f;
#pragma unroll
        for (int e = 0; e < NEXP; ++e) { lg[e] = acc[e] + rb[e]; mx = fmaxf(mx, lg[e]); }
        float s = 0.f;
#pragma unroll
        for (int e = 0; e < NEXP; ++e) { p[e] = expf(lg[e] - mx); s += p[e]; }
        float inv = 1.f / s;
#pragma unroll
        for (int e = 0; e < NEXP; ++e) p[e] *= inv;
        int i1 = 0;
#pragma unroll
        for (int e = 1; e < NEXP; ++e) if (p[e] > p[i1]) i1 = e;   // strict > == lowest-index tie rule
        int i2 = (i1 == 0) ? 1 : 0;
#pragma unroll
        for (int e = 0; e < NEXP; ++e) if (e != i1 && p[e] > p[i2]) i2 = e;
        top_e[2 * t]     = i1;  top_w[2 * t]     = p[i1];
        top_e[2 * t + 1] = i2;  top_w[2 * t + 1] = p[i2];
        atomicAdd(&cnt[i1], 1);
        atomicAdd(&cnt[i2], 1);
    }
}

// ---------------- per-expert 256-aligned segment offsets ----------------
__global__ void offsets_kernel(const int* __restrict__ cnt, int* __restrict__ poff) {
    if (threadIdx.x == 0) {
        int acc = 0;
#pragma unroll
        for (int e = 0; e < NEXP; ++e) { poff[e] = acc; acc += (cnt[e] + 255) & ~255; }
        poff[NEXP] = acc;   // padded total (<= CAPPAD)
    }
}

// ---------------- slot assignment ----------------
__global__ __launch_bounds__(256)
void assign_kernel(const int* __restrict__ top_e, const int* __restrict__ poff,
                   int* __restrict__ cursor, int* __restrict__ slot_of,
                   int* __restrict__ rowtok) {
    int t = blockIdx.x * 256 + threadIdx.x;
#pragma unroll
    for (int k = 0; k < 2; ++k) {
        int e = top_e[2 * t + k];
        int s = poff[e] + atomicAdd(&cursor[e], 1);
        slot_of[2 * t + k] = s;
        rowtok[s] = t;
    }
}

// ---------------- gather + fp32->bf16 convert ----------------
__global__ __launch_bounds__(256)
void gather_kernel(const float* __restrict__ x, const int* __restrict__ rowtok,
                   unsigned short* __restrict__ xg) {
    int row = blockIdx.x;
    int t = (row >= CAPPAD) ? (row - CAPPAD) : rowtok[row];
    ushort4* dst = (ushort4*)(xg + (size_t)row * DIM) + threadIdx.x;
    if (t < 0) { ushort4 z; z.x = z.y = z.z = z.w = 0; *dst = z; return; }
    float4 v = ((const float4*)(x + (size_t)t * DIM))[threadIdx.x];
    ushort4 o; o.x = f2bf(v.x); o.y = f2bf(v.y); o.z = f2bf(v.z); o.w = f2bf(v.w);
    *dst = o;
}

// ---------------- transpose + convert: fp32 [R][C] -> bf16 [C][R], vectorized both sides ----------
__global__ __launch_bounds__(256)
void transpose_convert(const float* __restrict__ in, unsigned short* __restrict__ out,
                       int R, int C) {
    __shared__ __align__(16) unsigned short tb[128][128];   // XOR-swizzled cols
    const size_t bofs = (size_t)blockIdx.z * R * C;
    const int r0 = blockIdx.y * 128, c0 = blockIdx.x * 128;
    const int lr = threadIdx.x >> 5;          // 0..7
    const int lc = threadIdx.x & 31;          // 0..31
#pragma unroll
    for (int s_ = 0; s_ < 16; ++s_) {
        int r = s_ * 8 + lr;
        float4 v = *(const float4*)&in[bofs + (size_t)(r0 + r) * C + c0 + lc * 4];
        ushort4 o; o.x = f2bf(v.x); o.y = f2bf(v.y); o.z = f2bf(v.z); o.w = f2bf(v.w);
        *(ushort4*)&tb[r][(lc * 4) ^ (r & 124)] = o;        // bank-spread, keeps 8B align
    }
    __syncthreads();
#pragma unroll
    for (int s_ = 0; s_ < 16; ++s_) {
        int c = s_ * 8 + lr;          // out row (= input col)
        int rb_ = lc * 4;             // out col group (= input row), swz row-bits equal for rb_..rb_+3
        ushort4 o;
        o.x = tb[rb_ + 0][c ^ rb_];
        o.y = tb[rb_ + 1][c ^ rb_];
        o.z = tb[rb_ + 2][c ^ rb_];
        o.w = tb[rb_ + 3][c ^ rb_];
        *(ushort4*)&out[bofs + (size_t)(c0 + c) * R + r0 + rb_] = o;
    }
}

// ---------------- 256x256 8-phase bf16 MFMA GEMM (T1+T2+T3+T4+T5) ----------------
// A: [MTOT][K] bf16 row-major. Wt: [NEXP][N][K] bf16 (B^T). SWt: [N][K] for shared rows.
// GELU=true: bf16 H = gelu(acc+bias); else f32 Y = acc+bias.
// vmcnt ledger (per thread, 2 loads per stage):
//   prologue: stage A0,B0,B1,A1 (8 out) -> vmcnt(4) drains A0,B0 -> entry state {B1,A1}=4
//   steady tile: ph0 +A0'(6) vmcnt(4) drains B1 | ph1 +B0'(6) vmcnt(4) drains A1
//                ph2 +B1'(6) | ph3 +A1'(8) vmcnt(4) drains A0',B0' -> exit {B1',A1'}=4
//   LAST tile (no prefetch): ph0 vmcnt(2) drains B1 | ph1 vmcnt(0) drains A1 | ph3 no wait
template <int N, int K, bool GELU>
__global__ __launch_bounds__(512, 2)
void gemm256_kernel(const unsigned short* __restrict__ A,
                    const unsigned short* __restrict__ Wt,
                    const unsigned short* __restrict__ SWt,
                    const float* __restrict__ Bias, const float* __restrict__ SBias,
                    const int* __restrict__ poff, void* __restrict__ Out,
                    int nwg, int ncol) {
    // LDS: 2 dbuf x 2 halves x [128 rows][64 k] bf16 for A and B = 128 KiB
    __shared__ __align__(16) unsigned short As[2][2][128 * 64];
    __shared__ __align__(16) unsigned short Bs[2][2][128 * 64];

    const int tid  = threadIdx.x;
    const int lane = tid & 63;
    const int wid  = tid >> 6;          // 0..7
    const int wr   = wid >> 2;          // 0..1 (row sub-block within a 128-half)
    const int wc   = wid & 3;           // 0..3 (col sub-block within a 128-half)

    const int wg  = xcd_swizzle(blockIdx.x, nwg);
    const int bx  = wg % ncol, by = wg / ncol;
    const int row0 = by * 256, col0 = bx * 256;

    const unsigned short* Bt; const float* bias;
    if (row0 >= CAPPAD) { Bt = SWt; bias = SBias; }
    else {
        int e = 0;
#pragma unroll
        for (int i = 1; i < NEXP; ++i) e += (row0 >= poff[i]);
        Bt = Wt + (size_t)e * N * K; bias = Bias + (size_t)e * N;
    }

    constexpr int NT = K / 64;
    static_assert(NT >= 2, "need >=2 k-tiles");

    // stage one half-tile: 1024 16B-chunks, 2 per thread; source pre-swizzled so
    // linear LDS dest holds chunk s = slot ^ (r&7)  (T2 both-sides swizzle, rule #21)
    auto stage = [&](const unsigned short* gbase, unsigned short* lds) {
#pragma unroll
        for (int i = 0; i < 2; ++i) {
            int c = i * 512 + tid;
            int r = c >> 3;
            int s = (c & 7) ^ (r & 7);
            async_ld16(gbase + (size_t)r * K + s * 8, lds + c * 8);
        }
    };

    f32x4 acc[2][2][4][2];   // [mh][nh][m'][n']
#pragma unroll
    for (int a0 = 0; a0 < 2; ++a0)
#pragma unroll
        for (int a1 = 0; a1 < 2; ++a1)
#pragma unroll
            for (int a2 = 0; a2 < 4; ++a2)
#pragma unroll
                for (int a3 = 0; a3 < 2; ++a3) acc[a0][a1][a2][a3] = (f32x4){0.f, 0.f, 0.f, 0.f};

    bf16x8 af[4][2];             // current mh A-frags
    bf16x8 bf0[2][2], bf1[2][2]; // B-frags for nh=0 / nh=1

    // frag LDS address helpers (with T2 read-side XOR)
    auto lda = [&](int b, int mh, int mp, int kk) -> bf16x8 {
        int r = wr * 64 + mp * 16 + (lane & 15);
        int q = kk * 4 + (lane >> 4);
        return *(const bf16x8*)&As[b][mh][r * 64 + ((q ^ (r & 7)) * 8)];
    };
    auto ldb = [&](int b, int nh, int np, int kk) -> bf16x8 {
        int r = wc * 32 + np * 16 + (lane & 15);
        int q = kk * 4 + (lane >> 4);
        return *(const bf16x8*)&Bs[b][nh][r * 64 + ((q ^ (r & 7)) * 8)];
    };

    // ---- prologue: stage tile 0, order [A0, B0, B1, A1]; drain own A0,B0 ----
    stage(A  + (size_t)(row0 +   0) * K, &As[0][0][0]);
    stage(Bt + (size_t)(col0 +   0) * K, &Bs[0][0][0]);
    stage(Bt + (size_t)(col0 + 128) * K, &Bs[0][1][0]);
    stage(A  + (size_t)(row0 + 128) * K, &As[0][1][0]);
    VMCNT4();
    BAR();

    for (int t = 0; t < NT; ++t) {
        const int b  = t & 1;
        const bool pf = (t + 1 < NT);
        const int kb1 = (t + 1) * 64;

        // ---- phase 0: quad (mh=0, nh=0); reads A0+B0; stage t+1 A0 ----
#pragma unroll
        for (int mp = 0; mp < 4; ++mp) { af[mp][0] = lda(b, 0, mp, 0); af[mp][1] = lda(b, 0, mp, 1); }
#pragma unroll
        for (int np = 0; np < 2; ++np) { bf0[np][0] = ldb(b, 0, np, 0); bf0[np][1] = ldb(b, 0, np, 1); }
        if (pf) stage(A + (size_t)(row0 + 0) * K + kb1, &As[b ^ 1][0][0]);
        BAR();
        __builtin_amdgcn_s_setprio(1);
#pragma unroll
        for (int kk = 0; kk < 2; ++kk)
#pragma unroll
            for (int mp = 0; mp < 4; ++mp)
#pragma unroll
                for (int np = 0; np < 2; ++np)
                    acc[0][0][mp][np] = __builtin_amdgcn_mfma_f32_16x16x32_bf16(af[mp][kk], bf0[np][kk], acc[0][0][mp][np], 0, 0, 0);
        __builtin_amdgcn_s_setprio(0);
        if (pf) VMCNT4(); else VMCNT2();   // drain B1 of tile t
        BAR();

        // ---- phase 1: quad (0,1); reads B1; stage t+1 B0 ----
#pragma unroll
        for (int np = 0; np < 2; ++np) { bf1[np][0] = ldb(b, 1, np, 0); bf1[np][1] = ldb(b, 1, np, 1); }
        if (pf) stage(Bt + (size_t)(col0 + 0) * K + kb1, &Bs[b ^ 1][0][0]);
        BAR();
        __builtin_amdgcn_s_setprio(1);
#pragma unroll
        for (int kk = 0; kk < 2; ++kk)
#pragma unroll
            for (int mp = 0; mp < 4; ++mp)
#pragma unroll
                for (int np = 0; np < 2; ++np)
                    acc[0][1][mp][np] = __builtin_amdgcn_mfma_f32_16x16x32_bf16(af[mp][kk], bf1[np][kk], acc[0][1][mp][np], 0, 0, 0);
        __builtin_amdgcn_s_setprio(0);
        if (pf) VMCNT4(); else VMCNT0();   // drain A1 of tile t
        BAR();

        // ---- phase 2: quad (1,1); reads A1; stage t+1 B1 ----
#pragma unroll
        for (int mp = 0; mp < 4; ++mp) { af[mp][0] = lda(b, 1, mp, 0); af[mp][1] = lda(b, 1, mp, 1); }
        if (pf) stage(Bt + (size_t)(col0 + 128) * K + kb1, &Bs[b ^ 1][1][0]);
        BAR();
        __builtin_amdgcn_s_setprio(1);
#pragma unroll
        for (int kk = 0; kk < 2; ++kk)
#pragma unroll
            for (int mp = 0; mp < 4; ++mp)
#pragma unroll
                for (int np = 0; np < 2; ++np)
                    acc[1][1][mp][np] = __builtin_amdgcn_mfma_f32_16x16x32_bf16(af[mp][kk], bf1[np][kk], acc[1][1][mp][np], 0, 0, 0);
        __builtin_amdgcn_s_setprio(0);
        BAR();

        // ---- phase 3: quad (1,0); no LDS reads (bf0 alive in regs); stage t+1 A1 ----
        if (pf) stage(A + (size_t)(row0 + 128) * K + kb1, &As[b ^ 1][1][0]);
        BAR();
        __builtin_amdgcn_s_setprio(1);
#pragma unroll
        for (int kk = 0; kk < 2; ++kk)
#pragma unroll
            for (int mp = 0; mp < 4; ++mp)
#pragma unroll
                for (int np = 0; np < 2; ++np)
                    acc[1][0][mp][np] = __builtin_amdgcn_mfma_f32_16x16x32_bf16(af[mp][kk], bf0[np][kk], acc[1][0][mp][np], 0, 0, 0);
        __builtin_amdgcn_s_setprio(0);
        if (pf) VMCNT4();                  // drain A0,B0 of tile t+1 (last tile: nothing outstanding)
        BAR();
    }

    // ---- epilogue: C/D layout col=lane&15, row=(lane>>4)*4+j ----
#pragma unroll
    for (int mh = 0; mh < 2; ++mh)
#pragma unroll
        for (int nh = 0; nh < 2; ++nh)
#pragma unroll
            for (int np = 0; np < 2; ++np) {
                const int col = col0 + nh * 128 + wc * 32 + np * 16 + (lane & 15);
                const float bv = bias[col];
#pragma unroll
                for (int mp = 0; mp < 4; ++mp) {
#pragma unroll
                    for (int j = 0; j < 4; ++j) {
                        const int row = row0 + mh * 128 + wr * 64 + mp * 16 + ((lane >> 4) << 2) + j;
                        float v = acc[mh][nh][mp][np][j] + bv;
                        if (GELU) {
                            v = 0.5f * v * (1.f + erff(v * 0.70710678118654752f));
                            ((unsigned short*)Out)[(size_t)row * N + col] = f2bf(v);
                        } else {
                            ((float*)Out)[(size_t)row * N + col] = v;
                        }
                    }
                }
            }
}

// ---------------- final combine: out = shared + w0*expert0 + w1*expert1 ----------------
__global__ __launch_bounds__(256)
void combine_kernel(const float* __restrict__ Y, const int* __restrict__ slot_of,
                    const float* __restrict__ top_w, float* __restrict__ out) {
    const int t = blockIdx.x, i = threadIdx.x;
    const int s0 = slot_of[2 * t], s1 = slot_of[2 * t + 1];
    const float w0 = top_w[2 * t], w1 = top_w[2 * t + 1];
    float4 ys = ((const float4*)(Y + (size_t)(CAPPAD + t) * DIM))[i];
    float4 y0 = ((const float4*)(Y + (size_t)s0 * DIM))[i];
    float4 y1 = ((const float4*)(Y + (size_t)s1 * DIM))[i];
    float4 r;
    r.x = ys.x + w0 * y0.x + w1 * y1.x;
    r.y = ys.y + w0 * y0.y + w1 * y1.y;
    r.z = ys.z + w0 * y0.z + w1 * y1.z;
    r.w = ys.w + w0 * y0.w + w1 * y1.w;
    ((float4*)(out + (size_t)t * DIM))[i] = r;
}

// ---------------- host launch ----------------
extern "C" void kernel_launch(void* const* d_in, const int* in_sizes, int n_in,
                              void* d_out, int out_size, void* d_ws, size_t ws_size,
                              hipStream_t stream) {
    const float* x   = (const float*)d_in[0];
    const float* rw  = (const float*)d_in[1];
    const float* rb  = (const float*)d_in[2];
    const float* w1  = (const float*)d_in[3];
    const float* b1  = (const float*)d_in[4];
    const float* w2  = (const float*)d_in[5];
    const float* b2  = (const float*)d_in[6];
    const float* sw1 = (const float*)d_in[7];
    const float* sb1 = (const float*)d_in[8];
    const float* sw2 = (const float*)d_in[9];
    const float* sb2 = (const float*)d_in[10];
    float* out = (float*)d_out;

    char* ws = (char*)d_ws;
    size_t off = 0;
    auto alloc = [&](size_t bytes) {
        off = (off + 255) & ~(size_t)255;
        size_t p = off; off += bytes; return p;
    };
    int*   meta    = (int*)(ws + alloc(32 * sizeof(int)));
    int*   cnt     = meta;
    int*   cursor  = meta + 8;
    int*   poff    = meta + 16;
    int*   top_e   = (int*)  (ws + alloc((size_t)2 * T_TOK * 4));
    float* top_w   = (float*)(ws + alloc((size_t)2 * T_TOK * 4));
    int*   slot_of = (int*)  (ws + alloc((size_t)2 * T_TOK * 4));
    int*   rowtok  = (int*)  (ws + alloc((size_t)CAPPAD * 4));
    unsigned short* xg   = (unsigned short*)(ws + alloc((size_t)MTOT * DIM * 2));
    size_t w1t_off = alloc((size_t)NEXP * HID * DIM * 2);
    unsigned short* w1t  = (unsigned short*)(ws + w1t_off);
    unsigned short* w2t  = (unsigned short*)(ws + alloc((size_t)NEXP * DIM * HID * 2));
    unsigned short* sw1t = (unsigned short*)(ws + alloc((size_t)HID * DIM * 2));
    unsigned short* sw2t = (unsigned short*)(ws + alloc((size_t)DIM * HID * 2));
    unsigned short* H    = (unsigned short*)(ws + alloc((size_t)MTOT * HID * 2));
    float*          Y    = (float*)(ws + w1t_off);   // alias: w1t dead after GEMM1 (58.7MB <= 67MB)

    hipMemsetAsync(meta, 0, 16 * sizeof(int), stream);          // cnt + cursor = 0
    hipMemsetAsync(rowtok, 0xFF, (size_t)CAPPAD * 4, stream);   // rowtok = -1

    // weight transpose+convert: fp32 [R][C] -> bf16 [C][R]
    transpose_convert<<<dim3(HID / 128, DIM / 128, NEXP), 256, 0, stream>>>(w1,  w1t,  DIM, HID);
    transpose_convert<<<dim3(DIM / 128, HID / 128, NEXP), 256, 0, stream>>>(w2,  w2t,  HID, DIM);
    transpose_convert<<<dim3(HID / 128, DIM / 128, 1),    256, 0, stream>>>(sw1, sw1t, DIM, HID);
    transpose_convert<<<dim3(DIM / 128, HID / 128, 1),    256, 0, stream>>>(sw2, sw2t, HID, DIM);

    router_kernel<<<T_TOK / 4, 256, 0, stream>>>(x, rw, rb, cnt, top_e, top_w);
    offsets_kernel<<<1, 64, 0, stream>>>(cnt, poff);
    assign_kernel<<<T_TOK / 256, 256, 0, stream>>>(top_e, poff, cursor, slot_of, rowtok);
    gather_kernel<<<MTOT, 256, 0, stream>>>(x, rowtok, xg);

    {   // GEMM1: [MTOT x 1024] x [4096 x 1024]^T -> H (gelu, bf16)
        const int ncol = HID / 256, nwg = ncol * (MTOT / 256);
        gemm256_kernel<HID, DIM, true><<<nwg, 512, 0, stream>>>(
            xg, w1t, sw1t, b1, sb1, poff, (void*)H, nwg, ncol);
    }
    {   // GEMM2: [MTOT x 4096] x [1024 x 4096]^T -> Y (f32)
        const int ncol = DIM / 256, nwg = ncol * (MTOT / 256);
        gemm256_kernel<DIM, HID, false><<<nwg, 512, 0, stream>>>(
            H, w2t, sw2t, b2, sb2, poff, (void*)Y, nwg, ncol);
    }

    combine_kernel<<<T_TOK, 256, 0, stream>>>(Y, slot_of, top_w, out);
}